// Round 12
// baseline (233.247 us; speedup 1.0000x reference)
//
#include <hip/hip_runtime.h>

// ---------------------------------------------------------------------------
// DeepCapsNet forward. conv2 = MFMA (bf16 hh+hl+lh split), r7 structure.
// R12: conv1 writes via LDS staging -> coalesced 1KB/wave global stores
// (r11's direct stores were 64 scattered 16B stores/wave, ~4x write amp).
// Workspace layout (dwords):
//   h1 : [0,        23658496)  ushort bf16, per (bi,chunk) block of 11552 dw:
//        hiE[4][190][8] | hiO[4][171][8] | loE | loO
//   Uws: [23658496, 23789568)  f32, [b][c=256]
//   Bt : [23789568, 24084480)  u32, [sidx][cot][hi/lo][n=128][16dw]
//   w3T: [24084480, 24105216)  f32, [p=81][c=256]
//   Wr1: [24105216, 24170752)  f32, [j=8][i,k,l]
//   Wr2: [24170752, 24236288)  f32
//   Wr3: [24236288, 24277248)  f32
// total 97,108,992 bytes
// ---------------------------------------------------------------------------

typedef __attribute__((ext_vector_type(8))) short short8;   // 8 bf16
typedef __attribute__((ext_vector_type(4))) float f32x4;

__device__ __forceinline__ ushort f2bf(float x) {
    uint u = __float_as_uint(x);
    return (ushort)((u + 0x7FFFu + ((u >> 16) & 1u)) >> 16);
}
__device__ __forceinline__ void bfsplit(float x, ushort& h, ushort& l) {
    h = f2bf(x);
    float hf = __uint_as_float(((uint)h) << 16);
    l = f2bf(x - hf);
}

// ---------------- merged prep: Bt + w3T + Wr ------------------------------
__global__ __launch_bounds__(256) void k_prep(
    const float* __restrict__ w2, uint* __restrict__ Bt,
    const float* __restrict__ w3, float* __restrict__ w3T,
    const float* __restrict__ W1, const float* __restrict__ W2,
    const float* __restrict__ W3, float* __restrict__ Wr1,
    float* __restrict__ Wr2, float* __restrict__ Wr3) {
    __shared__ __align__(16) float wbuf[64 * 288];
    const int b = blockIdx.x, t = threadIdx.x;
    if (b < 144) {            // ---- Bt: [sidx][cot][hi/lo][n=128][16dw]
        const int sidx = b >> 2, coq = b & 3;
        const int chunk = sidx / 9, tap = sidx - chunk * 9;
        const int co0 = coq * 64;
        for (int idx = t; idx < 4608; idx += 256) {
            const int n = idx / 72, q = idx - n * 72;
            ((float4*)wbuf)[n * 72 + q] =
                *(const float4*)(w2 + (size_t)(co0 + n) * 1152 + chunk * 288 + q * 4);
        }
        __syncthreads();
        const int n = t & 63, dg = (t >> 6) * 4;
        const int cot = coq >> 1, nn = ((coq & 1) * 64) + n;
        uint* dst = Bt + (size_t)(sidx * 2 + cot) * 4096;
#pragma unroll
        for (int dd = 0; dd < 4; ++dd) {
            const int d = dg + dd;
            const float x = wbuf[n * 288 + (2 * d) * 9 + tap];
            const float y = wbuf[n * 288 + (2 * d + 1) * 9 + tap];
            ushort xh, xl, yh, yl;
            bfsplit(x, xh, xl);
            bfsplit(y, yh, yl);
            dst[nn * 16 + d]        = (uint)xh | ((uint)yh << 16);
            dst[2048 + nn * 16 + d] = (uint)xl | ((uint)yl << 16);
        }
    } else if (b < 225) {     // ---- w3T
        const int p = b - 144;
        w3T[p * 256 + t] = w3[t * 81 + p];
    } else {                  // ---- Wr: [j][(i,k,l)]
        const int bb = b - 225;
        const int layer = bb >> 5, blk = bb & 31;
        const float* src = layer == 0 ? W1 : (layer == 1 ? W2 : W3);
        float* dst = layer == 0 ? Wr1 : (layer == 1 ? Wr2 : Wr3);
        const int d_h = (layer == 2) ? 16 : 8;
        const int total = (layer == 2) ? 5120 : 8192;
        for (int idx = blk * 256 + t; idx < 8 * total; idx += 32 * 256) {
            const int j = idx / total, e = idx - j * total;
            const int ik = e / d_h, l = e - ik * d_h;
            dst[idx] = src[(ik * 8 + j) * d_h + l];
        }
    }
}

// ---------------- conv1: LDS-staged output, one block per image ------------
// Per chunk: threads (ol = t>>6, pg = t&63) compute 32 ch x 361 pos into a
// 46.2KB LDS image (exact h1 chunk-block layout), then flat uint4 copy out
// (1KB/wave-instr, fully coalesced). Weights per chunk: 72 regs via LDS
// broadcast. LDS 57.9KB -> 2 blocks/CU.
__global__ __launch_bounds__(256, 2) void k_conv1(
    const float* __restrict__ x, const float* __restrict__ w,
    const float* __restrict__ bias, const float* __restrict__ g,
    const float* __restrict__ bb, const float* __restrict__ bm,
    const float* __restrict__ bv, ushort* __restrict__ h1) {
    __shared__ __align__(16) float xs[1521];
    __shared__ float wls[1152];
    __shared__ float2 scsh[128];
    __shared__ __align__(16) uint stage[11552];     // one chunk image
    const int b = blockIdx.x, t = threadIdx.x;
    const float* xb = x + (size_t)b * 1521;
    for (int i = t; i < 1521; i += 256) xs[i] = xb[i];
    for (int i = t; i < 1152; i += 256) wls[i] = w[i];
    if (t < 128) {
        const float inv = g[t] * rsqrtf(bv[t] + 1e-5f);
        scsh[t] = make_float2(inv, bias[t] * inv + bb[t] - bm[t] * inv);
    }
    const int ol = t >> 6, pg = t & 63;
    ushort* stg = (ushort*)stage;
    __syncthreads();
    for (int chunk = 0; chunk < 4; ++chunk) {
        // per-chunk weights into registers (same-address broadcast reads)
        float wr[8][9];
        float2 ss[8];
#pragma unroll
        for (int j = 0; j < 8; ++j) {
            const int c = chunk * 32 + ol * 8 + j;
#pragma unroll
            for (int k = 0; k < 9; ++k) wr[j][k] = wls[c * 9 + k];
            ss[j] = scsh[c];
        }
        for (int p = pg; p < 361; p += 64) {
            const int y = p / 19, xq = p - y * 19;
            const int base = y * 78 + xq * 2;
            const float x0 = xs[base],      x1 = xs[base + 1],  x2 = xs[base + 2];
            const float x3 = xs[base + 39], x4 = xs[base + 40], x5 = xs[base + 41];
            const float x6 = xs[base + 78], x7 = xs[base + 79], x8 = xs[base + 80];
            short8 hs, ls;
#pragma unroll
            for (int j = 0; j < 8; ++j) {
                const float acc = x0 * wr[j][0] + x1 * wr[j][1] + x2 * wr[j][2] +
                                  x3 * wr[j][3] + x4 * wr[j][4] + x5 * wr[j][5] +
                                  x6 * wr[j][6] + x7 * wr[j][7] + x8 * wr[j][8];
                const float v = fmaxf(fmaf(acc, ss[j].x, ss[j].y), 0.0f);
                ushort hh, lw;
                bfsplit(v, hh, lw);
                hs[j] = (short)hh;
                ls[j] = (short)lw;
            }
            if ((xq & 1) == 0) {
                const int pos = y * 10 + (xq >> 1);
                *(short8*)(stg + ol * 1520 + pos * 8)         = hs;
                *(short8*)(stg + 11552 + ol * 1520 + pos * 8) = ls;
            } else {
                const int pos = y * 9 + (xq >> 1);
                *(short8*)(stg + 6080 + ol * 1368 + pos * 8)  = hs;
                *(short8*)(stg + 17632 + ol * 1368 + pos * 8) = ls;
            }
        }
        __syncthreads();
        {   // flat coalesced copy: 2888 uint4
            uint4* dst = (uint4*)(h1 + (size_t)b * 92416 + chunk * 23104);
            const uint4* src = (const uint4*)stage;
#pragma unroll
            for (int k = 0; k < 11; ++k) dst[t + k * 256] = src[t + k * 256];
            if (t < 72) dst[t + 11 * 256] = src[t + 11 * 256];
        }
        __syncthreads();
    }
}

// ---------------- conv2: r7 structure --------------------------------------
// One block per (image, co-half). M=81 (pad 96), N=128, K = 4x9x32.
// 4 waves, wave 48x64. LDS = one (bi,chunk) h1 block (46.2 KB) -> 3 blocks/CU.
// B fragments prefetched one tap ahead in regs; conv3 fused in epilogue.
__global__ __launch_bounds__(256, 3) void k_conv2(
    const uint* __restrict__ h1u, const uint* __restrict__ Bt,
    const float* __restrict__ g,
    const float* __restrict__ bb, const float* __restrict__ bm,
    const float* __restrict__ bv, const float* __restrict__ bias,
    const float* __restrict__ w3T, float* __restrict__ Uws) {
    __shared__ __align__(16) uint raw[11552];
    __shared__ float ured[128];
    const int t = threadIdx.x;
    const int lane = t & 63, wave = t >> 6;
    const int ln15 = lane & 15, lq = lane >> 4;
    const int wm = (wave >> 1) * 48, wn = (wave & 1) * 64;
    const int gg = blockIdx.x;
    const int bi  = ((gg >> 4) << 3) | (gg & 7);   // XCD-pair swizzle
    const int cot = (gg >> 3) & 1;
    const int co0 = cot * 128;

    int PE[3], PO[3];
#pragma unroll
    for (int i = 0; i < 3; ++i) {
        const int m = wm + i * 16 + ln15;
        const int p = m < 81 ? m : 80;       // pad rows clamp
        const int oh = p / 9, ow = p - oh * 9;
        PE[i] = lq * 760 + oh * 80 + ow * 4;
        PO[i] = 3040 + lq * 684 + oh * 72 + ow * 4;
    }
    int BRDg[4];
#pragma unroll
    for (int j = 0; j < 4; ++j) {
        const int n = wn + j * 16 + ln15;
        BRDg[j] = n * 16 + lq * 4;
    }

    f32x4 acc[3][4] = {};
    uint4 Bn[8];
    {   // prologue: prefetch s = 0
        const uint* bp = Bt + (size_t)cot * 4096;
#pragma unroll
        for (int j = 0; j < 4; ++j) {
            Bn[j]     = *(const uint4*)(bp + BRDg[j]);
            Bn[4 + j] = *(const uint4*)(bp + 2048 + BRDg[j]);
        }
    }

#pragma unroll
    for (int c = 0; c < 4; ++c) {
        __syncthreads();
        {   // stage the (bi,chunk) block: clustered loads then stores
            const uint4* src = (const uint4*)(h1u + (size_t)(bi * 4 + c) * 11552);
            uint4* dst = (uint4*)raw;
            uint4 tmp[11];
#pragma unroll
            for (int k = 0; k < 11; ++k) tmp[k] = src[t + k * 256];
            const bool extra = (t < 72);
            uint4 te;
            if (extra) te = src[t + 11 * 256];
#pragma unroll
            for (int k = 0; k < 11; ++k) dst[t + k * 256] = tmp[k];
            if (extra) dst[t + 11 * 256] = te;
        }
        __syncthreads();
        short8 a_h[3];
#pragma unroll
        for (int i = 0; i < 3; ++i)
            a_h[i] = *reinterpret_cast<const short8*>(raw + PE[i]);
#pragma unroll
        for (int tap = 0; tap < 9; ++tap) {
            const int s = c * 9 + tap;
            uint4 Bc[8];
#pragma unroll
            for (int q = 0; q < 8; ++q) Bc[q] = Bn[q];
            if (s < 35) {
                const uint* bp = Bt + (size_t)((s + 1) * 2 + cot) * 4096;
#pragma unroll
                for (int j = 0; j < 4; ++j) {
                    Bn[j]     = *(const uint4*)(bp + BRDg[j]);
                    Bn[4 + j] = *(const uint4*)(bp + 2048 + BRDg[j]);
                }
            }
            const int kh = tap / 3, kw = tap - kh * 3;
            const int odd = kw & 1;
            const int sE = kh * 40 + (kw >> 1) * 4;
            const int sO = kh * 36;
            short8 a_l[3];
#pragma unroll
            for (int i = 0; i < 3; ++i) {
                const int addr = odd ? (PO[i] + sO) : (PE[i] + sE);
                a_l[i] = *reinterpret_cast<const short8*>(raw + addr + 5776);
            }
            short8 a_hn[3];
            if (tap < 8) {
                const int tap2 = tap + 1;
                const int kh2 = tap2 / 3, kw2 = tap2 - kh2 * 3;
                const int odd2 = kw2 & 1;
                const int sE2 = kh2 * 40 + (kw2 >> 1) * 4;
                const int sO2 = kh2 * 36;
#pragma unroll
                for (int i = 0; i < 3; ++i) {
                    const int addr2 = odd2 ? (PO[i] + sO2) : (PE[i] + sE2);
                    a_hn[i] = *reinterpret_cast<const short8*>(raw + addr2);
                }
            }
            short8 bh[4], bl[4];
#pragma unroll
            for (int j = 0; j < 4; ++j) {
                bh[j] = __builtin_bit_cast(short8, Bc[j]);
                bl[j] = __builtin_bit_cast(short8, Bc[4 + j]);
            }
#pragma unroll
            for (int i = 0; i < 3; ++i)
#pragma unroll
                for (int j = 0; j < 4; ++j)
                    acc[i][j] = __builtin_amdgcn_mfma_f32_16x16x32_bf16(a_h[i], bh[j], acc[i][j], 0, 0, 0);
#pragma unroll
            for (int i = 0; i < 3; ++i)
#pragma unroll
                for (int j = 0; j < 4; ++j)
                    acc[i][j] = __builtin_amdgcn_mfma_f32_16x16x32_bf16(a_h[i], bl[j], acc[i][j], 0, 0, 0);
#pragma unroll
            for (int i = 0; i < 3; ++i)
#pragma unroll
                for (int j = 0; j < 4; ++j)
                    acc[i][j] = __builtin_amdgcn_mfma_f32_16x16x32_bf16(a_l[i], bh[j], acc[i][j], 0, 0, 0);
            if (tap < 8) {
#pragma unroll
                for (int i = 0; i < 3; ++i) a_h[i] = a_hn[i];
            }
        }
    }

    // ---- epilogue: bn + relu + fused depthwise conv3 reduction ------------
    float scj[4], shj[4];
#pragma unroll
    for (int j = 0; j < 4; ++j) {
        const int co = co0 + wn + j * 16 + ln15;
        const float inv = g[co] * rsqrtf(bv[co] + 1e-5f);
        scj[j] = inv;
        shj[j] = bias[co] * inv + bb[co] - bm[co] * inv;
    }
    float usum[4] = {0.f, 0.f, 0.f, 0.f};
#pragma unroll
    for (int i = 0; i < 3; ++i)
#pragma unroll
        for (int r = 0; r < 4; ++r) {
            const int m = wm + i * 16 + lq * 4 + r;
            if (m < 81) {
                const float* wrow = w3T + m * 256 + co0;
#pragma unroll
                for (int j = 0; j < 4; ++j) {
                    const int col = wn + j * 16 + ln15;
                    const float v = fmaxf(fmaf(acc[i][j][r], scj[j], shj[j]), 0.0f);
                    usum[j] = fmaf(v, wrow[col], usum[j]);
                }
            }
        }
#pragma unroll
    for (int j = 0; j < 4; ++j) {
        usum[j] += __shfl_xor(usum[j], 16);
        usum[j] += __shfl_xor(usum[j], 32);
    }
    if (lq == 0 && wm == 0) {
#pragma unroll
        for (int j = 0; j < 4; ++j) ured[(wn >> 6) * 64 + j * 16 + ln15] = usum[j];
    }
    __syncthreads();
    if (lq == 0 && wm == 48) {
#pragma unroll
        for (int j = 0; j < 4; ++j) {
            const int col = wn + j * 16 + ln15;
            Uws[(size_t)bi * 256 + co0 + col] =
                usum[j] + ured[(wn >> 6) * 64 + j * 16 + ln15];
        }
    }
}

// ---------------- fused squash + 3x fccaps ---------------------------------
__device__ __forceinline__ void fccaps_block(
    const int n_l, const int n_h, const int d_h, const float* __restrict__ Wr,
    float* U, float* Uh, float* Sv, float* Av, float* Cv, float* coefs,
    float* outU, const int t) {
    const int nkd = n_h * d_h;
    const int total = n_l * nkd;
    __syncthreads();
    for (int e = t; e < total; e += 256) {
        const int i = e / nkd;
        const float* up = U + i * 8;
        float acc = 0.0f;
#pragma unroll
        for (int j = 0; j < 8; ++j) acc += up[j] * Wr[j * total + e];
        Uh[e] = acc;
    }
    __syncthreads();
    for (int e = t; e < nkd; e += 256) {
        float acc = 0.0f;
        for (int i = 0; i < n_l; ++i) acc += Uh[i * nkd + e];
        Sv[e] = acc;
    }
    __syncthreads();
    for (int e = t; e < n_l * n_h; e += 256) {
        const int h = e / n_h, k = e - h * n_h;
        float acc = 0.0f;
        for (int l = 0; l < d_h; ++l)
            acc += Uh[h * nkd + k * d_h + l] * Sv[k * d_h + l];
        Av[e] = acc;
    }
    __syncthreads();
    {   // parallel softmax over k: 8 lanes per row h
        const int h = t >> 3, sub = t & 7;
        const float invs = 1.0f / 2.8284271247461903f;
        float mx = -1e30f;
        for (int k = sub; k < n_h; k += 8) mx = fmaxf(mx, Av[h * n_h + k]);
        mx = fmaxf(mx, __shfl_xor(mx, 1));
        mx = fmaxf(mx, __shfl_xor(mx, 2));
        mx = fmaxf(mx, __shfl_xor(mx, 4));
        float sum = 0.0f;
        for (int k = sub; k < n_h; k += 8) {
            const float ev = expf((Av[h * n_h + k] - mx) * invs);
            Cv[h * n_h + k] = ev;
            sum += ev;
        }
        sum += __shfl_xor(sum, 1);
        sum += __shfl_xor(sum, 2);
        sum += __shfl_xor(sum, 4);
        const float r = 1.0f / sum;
        for (int k = sub; k < n_h; k += 8) Cv[h * n_h + k] *= r;
    }
    __syncthreads();
    for (int e = t; e < nkd; e += 256) {
        const int k = e / d_h;
        float acc = 0.0f;
        for (int i = 0; i < n_l; ++i) acc += Uh[i * nkd + e] * Cv[i * n_h + k];
        Sv[e] = acc;
    }
    __syncthreads();
    if (t < n_h) {
        float ssq = 0.0f;
        for (int l = 0; l < d_h; ++l) { const float uv = Sv[t * d_h + l]; ssq += uv * uv; }
        const float n = sqrtf(ssq);
        coefs[t] = (1.0f - 1.0f / (expf(n) + 1e-20f)) / (n + 1e-20f);
    }
    __syncthreads();
    for (int e = t; e < nkd; e += 256) outU[e] = Sv[e] * coefs[e / d_h];
}

__global__ __launch_bounds__(256) void k_caps(
    const float* __restrict__ Uws, const float* __restrict__ b3,
    const float* __restrict__ Wr1, const float* __restrict__ Wr2,
    const float* __restrict__ Wr3, float* __restrict__ out) {
    __shared__ float U[256];
    __shared__ float Uh[8192];
    __shared__ float Sv[256];
    __shared__ float Av[1024];
    __shared__ float Cv[1024];
    __shared__ float coefs[32];
    const int b = blockIdx.x, t = threadIdx.x;
    U[t] = Uws[(size_t)b * 256 + t] + b3[t];
    __syncthreads();
    if (t < 32) {
        float ssq = 0.0f;
        for (int j = 0; j < 8; ++j) { const float uv = U[t * 8 + j]; ssq += uv * uv; }
        const float n = sqrtf(ssq);
        coefs[t] = (1.0f - 1.0f / (expf(n) + 1e-20f)) / (n + 1e-20f);
    }
    __syncthreads();
    U[t] *= coefs[t >> 3];
    fccaps_block(32, 32,  8, Wr1, U, Uh, Sv, Av, Cv, coefs, U, t);
    fccaps_block(32, 32,  8, Wr2, U, Uh, Sv, Av, Cv, coefs, U, t);
    fccaps_block(32, 10, 16, Wr3, U, Uh, Sv, Av, Cv, coefs, out + (size_t)b * 160, t);
}

// ---------------------------------------------------------------------------
extern "C" void kernel_launch(void* const* d_in, const int* in_sizes, int n_in,
                              void* d_out, int out_size, void* d_ws, size_t ws_size,
                              hipStream_t stream) {
    const float* x    = (const float*)d_in[0];
    const float* c1w  = (const float*)d_in[1];
    const float* c1b  = (const float*)d_in[2];
    const float* bn1g = (const float*)d_in[3];
    const float* bn1b = (const float*)d_in[4];
    const float* bn1m = (const float*)d_in[5];
    const float* bn1v = (const float*)d_in[6];
    const float* c2w  = (const float*)d_in[7];
    const float* c2b  = (const float*)d_in[8];
    const float* bn2g = (const float*)d_in[9];
    const float* bn2b = (const float*)d_in[10];
    const float* bn2m = (const float*)d_in[11];
    const float* bn2v = (const float*)d_in[12];
    const float* c3w  = (const float*)d_in[13];
    const float* c3b  = (const float*)d_in[14];
    const float* W1   = (const float*)d_in[15];
    const float* W2   = (const float*)d_in[16];
    const float* W3   = (const float*)d_in[17];
    float* out = (float*)d_out;
    uint*  wsu = (uint*)d_ws;
    float* wsf = (float*)d_ws;

    ushort* h1  = (ushort*)wsu;          // 23,658,496 dw as bf16 planes
    float*  Uws = wsf + 23658496;        //    131,072 dw
    uint*   Bt  = wsu + 23789568;        //    294,912 dw
    float*  w3T = wsf + 24084480;        //     20,736 dw
    float*  Wr1 = wsf + 24105216;        //     65,536 dw
    float*  Wr2 = wsf + 24170752;        //     65,536 dw
    float*  Wr3 = wsf + 24236288;        //     40,960 dw

    k_prep<<<dim3(321), 256, 0, stream>>>(c2w, Bt, c3w, w3T, W1, W2, W3,
                                          Wr1, Wr2, Wr3);
    k_conv1<<<dim3(512), 256, 0, stream>>>(x, c1w, c1b, bn1g, bn1b, bn1m, bn1v, h1);
    k_conv2<<<dim3(1024), 256, 0, stream>>>((const uint*)h1, Bt, bn2g, bn2b, bn2m, bn2v,
                                            c2b, w3T, Uws);
    k_caps<<<dim3(512), 256, 0, stream>>>(Uws, c3b, Wr1, Wr2, Wr3, out);
}